// Round 1
// baseline (1829.718 us; speedup 1.0000x reference)
//
#include <hip/hip_runtime.h>
#include <hip/hip_bf16.h>

#define DIM 64
#define NREL 8

// ---------------- degree ----------------
__global__ __launch_bounds__(256) void deg_kernel(const int* __restrict__ dst,
                                                  float* __restrict__ deg, int E) {
    int i = blockIdx.x * blockDim.x + threadIdx.x;
    if (i < E) atomicAdd(&deg[dst[i]], 1.0f);
}

// ---------------- initial gather: x = node_emb[x_idx] ----------------
__global__ __launch_bounds__(256) void gather_kernel(const int* __restrict__ x_idx,
                                                     const float* __restrict__ emb,
                                                     float* __restrict__ x, int N) {
    int i = blockIdx.x * blockDim.x + threadIdx.x;   // over N*DIM
    if (i >= N * DIM) return;
    int n = i >> 6;           // /64
    int c = i & 63;
    x[i] = emb[(size_t)x_idx[n] * DIM + c];
}

// ---------------- scatter messages: agg[dst] += x[src] @ W[et] ----------------
// one wave per edge; lane = output channel
__global__ __launch_bounds__(256) void scatter_kernel(const float* __restrict__ x,
                                                      const int* __restrict__ src,
                                                      const int* __restrict__ dstv,
                                                      const int* __restrict__ et,
                                                      const float* __restrict__ W,   // [R,64,64] for this layer
                                                      float* __restrict__ agg, int E) {
    __shared__ float xs[4][DIM];
    int wave = threadIdx.x >> 6;
    int lane = threadIdx.x & 63;
    int e = blockIdx.x * 4 + wave;
    if (e >= E) return;
    int s = src[e];
    int d = dstv[e];
    int r = et[e];
    // stage x[src] in LDS so the k-loop reads are same-address broadcasts
    xs[wave][lane] = x[(size_t)s * DIM + lane];
    const float* Wr = W + (size_t)r * DIM * DIM;
    float acc = 0.f;
#pragma unroll
    for (int k = 0; k < DIM; ++k) {
        acc = fmaf(xs[wave][k], Wr[k * DIM + lane], acc);
    }
    atomicAdd(&agg[(size_t)d * DIM + lane], acc);
}

// ---------------- update: x_new = relu(agg*inv_deg + x@root + bias), in-place into agg ----------------
__global__ __launch_bounds__(256) void update_kernel(const float* __restrict__ x,
                                                     float* __restrict__ agg,   // in/out
                                                     const float* __restrict__ deg,
                                                     const float* __restrict__ root,  // [64,64]
                                                     const float* __restrict__ bias,  // [64]
                                                     int N) {
    __shared__ float xs[4][DIM];
    int wave = threadIdx.x >> 6;
    int lane = threadIdx.x & 63;
    int n = blockIdx.x * 4 + wave;
    if (n >= N) return;
    xs[wave][lane] = x[(size_t)n * DIM + lane];
    float inv = 1.0f / fmaxf(deg[n], 1.0f);
    float acc = bias[lane];
#pragma unroll
    for (int k = 0; k < DIM; ++k) {
        acc = fmaf(xs[wave][k], root[k * DIM + lane], acc);
    }
    float v = agg[(size_t)n * DIM + lane] * inv + acc;
    agg[(size_t)n * DIM + lane] = fmaxf(v, 0.f);
}

// ---------------- score: out[t] = dot(x[s], x[t]) ----------------
__global__ __launch_bounds__(256) void score_kernel(const float* __restrict__ x,
                                                    const int* __restrict__ s,
                                                    const int* __restrict__ t,
                                                    float* __restrict__ out, int T) {
    int wave = threadIdx.x >> 6;
    int lane = threadIdx.x & 63;
    int i = blockIdx.x * 4 + wave;
    if (i >= T) return;
    float p = x[(size_t)s[i] * DIM + lane] * x[(size_t)t[i] * DIM + lane];
#pragma unroll
    for (int off = 32; off > 0; off >>= 1) p += __shfl_down(p, off, 64);
    if (lane == 0) out[i] = p;
}

extern "C" void kernel_launch(void* const* d_in, const int* in_sizes, int n_in,
                              void* d_out, int out_size, void* d_ws, size_t ws_size,
                              hipStream_t stream) {
    const int*   x_idx  = (const int*)d_in[0];
    const int*   eidx   = (const int*)d_in[1];   // [2,E]
    const int*   etyp   = (const int*)d_in[2];   // [E]
    const int*   tidx   = (const int*)d_in[3];   // [2,T]
    const float* emb    = (const float*)d_in[4]; // [N,64]
    const float* weight = (const float*)d_in[5]; // [L,R,64,64]
    const float* root   = (const float*)d_in[6]; // [L,64,64]
    const float* bias   = (const float*)d_in[7]; // [L,64]

    int N = in_sizes[0];
    int E = in_sizes[2];
    int T = in_sizes[3] / 2;
    int L = in_sizes[5] / (NREL * DIM * DIM);

    const int* src = eidx;
    const int* dst = eidx + E;
    const int* ts  = tidx;
    const int* tt  = tidx + T;
    float* out = (float*)d_out;

    // workspace layout: buf0 [N*64], buf1 [N*64], deg [N]
    float* buf0 = (float*)d_ws;
    float* buf1 = buf0 + (size_t)N * DIM;
    float* deg  = buf1 + (size_t)N * DIM;

    // degree (once per call; ws is re-poisoned each call so always recompute)
    hipMemsetAsync(deg, 0, (size_t)N * sizeof(float), stream);
    deg_kernel<<<(E + 255) / 256, 256, 0, stream>>>(dst, deg, E);

    // x0 = node_emb[x_idx] -> buf0
    gather_kernel<<<((size_t)N * DIM + 255) / 256, 256, 0, stream>>>(x_idx, emb, buf0, N);

    float* xcur = buf0;
    float* aggb = buf1;
    for (int l = 0; l < L; ++l) {
        hipMemsetAsync(aggb, 0, (size_t)N * DIM * sizeof(float), stream);
        scatter_kernel<<<(E + 3) / 4, 256, 0, stream>>>(
            xcur, src, dst, etyp, weight + (size_t)l * NREL * DIM * DIM, aggb, E);
        update_kernel<<<(N + 3) / 4, 256, 0, stream>>>(
            xcur, aggb, deg, root + (size_t)l * DIM * DIM, bias + (size_t)l * DIM, N);
        // aggb now holds x_{l+1}; old xcur becomes scratch for next layer
        float* tmp = xcur; xcur = aggb; aggb = tmp;
    }

    score_kernel<<<(T + 3) / 4, 256, 0, stream>>>(xcur, ts, tt, out, T);
}

// Round 2
// 548.126 us; speedup vs baseline: 3.3381x; 3.3381x over previous
//
#include <hip/hip_runtime.h>
#include <hip/hip_bf16.h>

#define DIM 64
#define NREL 8
#define KTOT 576            // 8*64 relation block + 64 root block
#define WT_STRIDE 584       // padded LDS row stride (bf16 elems), 292 dwords -> 2-way max

typedef __bf16 bf16x8 __attribute__((ext_vector_type(8)));
typedef float  f32x4  __attribute__((ext_vector_type(4)));

// ---------------- int degree ----------------
__global__ __launch_bounds__(256) void deg_kernel(const int* __restrict__ dst,
                                                  int* __restrict__ degi, int E) {
    int i = blockIdx.x * blockDim.x + threadIdx.x;
    if (i < E) atomicAdd(&degi[dst[i]], 1);
}

__global__ __launch_bounds__(256) void invdeg_kernel(const int* __restrict__ degi,
                                                     float* __restrict__ invdeg, int N) {
    int i = blockIdx.x * blockDim.x + threadIdx.x;
    if (i < N) invdeg[i] = 1.0f / fmaxf((float)degi[i], 1.0f);
}

// ---------------- 3-kernel exclusive scan (offsets from degi) ----------------
__global__ __launch_bounds__(256) void scan1_kernel(const int* __restrict__ degi,
                                                    int* __restrict__ offs,
                                                    int* __restrict__ bsum, int N) {
    __shared__ int sd[256];
    int tid = threadIdx.x;
    int i = blockIdx.x * 256 + tid;
    int v = (i < N) ? degi[i] : 0;
    sd[tid] = v;
    __syncthreads();
#pragma unroll
    for (int off = 1; off < 256; off <<= 1) {
        int t = (tid >= off) ? sd[tid - off] : 0;
        __syncthreads();
        sd[tid] += t;
        __syncthreads();
    }
    if (i < N) offs[i] = sd[tid] - v;        // exclusive within block
    if (tid == 255) bsum[blockIdx.x] = sd[255];
}

__global__ __launch_bounds__(512) void scan2_kernel(int* __restrict__ bsum, int nb) {
    __shared__ int sd[512];
    int tid = threadIdx.x;
    int v = (tid < nb) ? bsum[tid] : 0;
    sd[tid] = v;
    __syncthreads();
#pragma unroll
    for (int off = 1; off < 512; off <<= 1) {
        int t = (tid >= off) ? sd[tid - off] : 0;
        __syncthreads();
        sd[tid] += t;
        __syncthreads();
    }
    if (tid < nb) bsum[tid] = sd[tid] - v;   // exclusive block bases
}

__global__ __launch_bounds__(256) void scan3_kernel(int* __restrict__ offs,
                                                    const int* __restrict__ bsum, int N) {
    int i = blockIdx.x * 256 + threadIdx.x;
    if (i < N) offs[i] += bsum[blockIdx.x];
}

// ---------------- bucket edges by dst: packed = src | (et<<24) ----------------
__global__ __launch_bounds__(256) void bucket_kernel(const int* __restrict__ src,
                                                     const int* __restrict__ dst,
                                                     const int* __restrict__ et,
                                                     const int* __restrict__ offs,
                                                     int* __restrict__ cursor,
                                                     unsigned* __restrict__ packed, int E) {
    int i = blockIdx.x * blockDim.x + threadIdx.x;
    if (i >= E) return;
    int d = dst[i];
    int p = offs[d] + atomicAdd(&cursor[d], 1);
    packed[p] = (unsigned)src[i] | ((unsigned)et[i] << 24);
}

// ---------------- initial gather: xb = bf16(node_emb[x_idx]) ----------------
__global__ __launch_bounds__(256) void gather_kernel(const int* __restrict__ x_idx,
                                                     const float* __restrict__ emb,
                                                     __bf16* __restrict__ xb, int N) {
    int i = blockIdx.x * blockDim.x + threadIdx.x;
    if (i >= N * DIM) return;
    int n = i >> 6;
    int c = i & 63;
    xb[i] = (__bf16)emb[(size_t)x_idx[n] * DIM + c];
}

// ---------------- aggregate: Sx[d, r*64+c] = inv_deg * sum_{e in(d),et=r} x[src][c]
//                  Sx[d, 512+c] = x[d][c]                        (one wave per dst)
__global__ __launch_bounds__(256) void aggregate_kernel(const __bf16* __restrict__ xb,
                                                        const unsigned* __restrict__ packed,
                                                        const int* __restrict__ offs,
                                                        const int* __restrict__ degi,
                                                        const float* __restrict__ invdeg,
                                                        __bf16* __restrict__ Sx, int N) {
    int d = blockIdx.x * 4 + (threadIdx.x >> 6);
    if (d >= N) return;
    int lane = threadIdx.x & 63;
    int base = offs[d];
    int ne = degi[d];
    float acc[NREL];
#pragma unroll
    for (int r = 0; r < NREL; ++r) acc[r] = 0.f;

    for (int j0 = 0; j0 < ne; j0 += 64) {
        int m = min(64, ne - j0);
        unsigned u = (lane < m) ? packed[base + j0 + lane] : 0u;
        for (int j = 0; j < m; ++j) {
            unsigned ue = __shfl(u, j, 64);
            int s = (int)(ue & 0xFFFFFFu);
            int r = (int)(ue >> 24);
            float xv = (float)xb[(size_t)s * DIM + lane];
#pragma unroll
            for (int rr = 0; rr < NREL; ++rr) acc[rr] += (r == rr) ? xv : 0.f;
        }
    }
    float inv = invdeg[d];
    __bf16* row = Sx + (size_t)d * KTOT;
#pragma unroll
    for (int rr = 0; rr < NREL; ++rr) row[rr * 64 + lane] = (__bf16)(acc[rr] * inv);
    row[512 + lane] = xb[(size_t)d * DIM + lane];
}

// ---------------- GEMM: xout = relu(Sx[N,576] @ Wcat[576,64] + bias), bf16 MFMA
// Wcat rows 0..511: weight[r][i][o] at k = r*64+i; rows 512..575: root[i][o].
// W^T staged in LDS (Wt[c][k]); A-frags streamed from global.
__global__ __launch_bounds__(256) void gemm_kernel(const __bf16* __restrict__ Sx,
                                                   const float* __restrict__ weight_l, // [8,64,64]
                                                   const float* __restrict__ root_l,   // [64,64]
                                                   const float* __restrict__ bias_l,   // [64]
                                                   __bf16* __restrict__ xout, int N) {
    __shared__ __bf16 Wt[64 * WT_STRIDE];

    // stage W^T (bf16) once per block
    for (int idx = threadIdx.x; idx < KTOT * 64; idx += 256) {
        int k = idx >> 6;
        int c = idx & 63;
        float w = (k < 512) ? weight_l[((k >> 6) << 12) + ((k & 63) << 6) + c]
                            : root_l[((k - 512) << 6) + c];
        Wt[c * WT_STRIDE + k] = (__bf16)w;
    }
    __syncthreads();

    int wave = threadIdx.x >> 6;
    int lane = threadIdx.x & 63;
    int l15 = lane & 15;
    int lg  = lane >> 4;            // 0..3
    int ntiles = (N + 63) >> 6;

    for (int tile = blockIdx.x; tile < ntiles; tile += gridDim.x) {
        int n0 = tile * 64;
        int row_a = n0 + 16 * wave + l15;
        if (row_a >= N) row_a = N - 1;                 // clamped load, store guarded
        const __bf16* arow = Sx + (size_t)row_a * KTOT + lg * 8;

        f32x4 acc[4];
#pragma unroll
        for (int t = 0; t < 4; ++t) acc[t] = (f32x4){0.f, 0.f, 0.f, 0.f};

#pragma unroll
        for (int k0 = 0; k0 < KTOT; k0 += 32) {
            bf16x8 av = *reinterpret_cast<const bf16x8*>(arow + k0);
#pragma unroll
            for (int t = 0; t < 4; ++t) {
                bf16x8 bv = *reinterpret_cast<const bf16x8*>(
                    &Wt[(16 * t + l15) * WT_STRIDE + k0 + lg * 8]);
                acc[t] = __builtin_amdgcn_mfma_f32_16x16x32_bf16(av, bv, acc[t], 0, 0, 0);
            }
        }

        // epilogue: D row = 4*lg + reg, col = 16*t + l15
#pragma unroll
        for (int t = 0; t < 4; ++t) {
            int c = 16 * t + l15;
            float b = bias_l[c];
#pragma unroll
            for (int i = 0; i < 4; ++i) {
                int n = n0 + 16 * wave + 4 * lg + i;
                if (n < N) {
                    float v = acc[t][i] + b;
                    xout[(size_t)n * DIM + c] = (__bf16)fmaxf(v, 0.f);
                }
            }
        }
    }
}

// ---------------- score: out[t] = dot(x[s], x[t]) ----------------
__global__ __launch_bounds__(256) void score_kernel(const __bf16* __restrict__ xb,
                                                    const int* __restrict__ s,
                                                    const int* __restrict__ t,
                                                    float* __restrict__ out, int T) {
    int i = blockIdx.x * 4 + (threadIdx.x >> 6);
    if (i >= T) return;
    int lane = threadIdx.x & 63;
    float p = (float)xb[(size_t)s[i] * DIM + lane] * (float)xb[(size_t)t[i] * DIM + lane];
#pragma unroll
    for (int off = 32; off > 0; off >>= 1) p += __shfl_down(p, off, 64);
    if (lane == 0) out[i] = p;
}

extern "C" void kernel_launch(void* const* d_in, const int* in_sizes, int n_in,
                              void* d_out, int out_size, void* d_ws, size_t ws_size,
                              hipStream_t stream) {
    const int*   x_idx  = (const int*)d_in[0];
    const int*   eidx   = (const int*)d_in[1];   // [2,E]
    const int*   etyp   = (const int*)d_in[2];   // [E]
    const int*   tidx   = (const int*)d_in[3];   // [2,T]
    const float* emb    = (const float*)d_in[4]; // [N,64]
    const float* weight = (const float*)d_in[5]; // [L,8,64,64]
    const float* root   = (const float*)d_in[6]; // [L,64,64]
    const float* bias   = (const float*)d_in[7]; // [L,64]

    int N = in_sizes[0];
    int E = in_sizes[2];
    int T = in_sizes[3] / 2;
    int L = in_sizes[5] / (NREL * DIM * DIM);

    const int* src = eidx;
    const int* dst = eidx + E;
    const int* ts  = tidx;
    const int* tt  = tidx + T;
    float* out = (float*)d_out;

    // ---- workspace carve-up (256B aligned chunks) ----
    char* p = (char*)d_ws;
    auto alloc = [&](size_t bytes) -> void* {
        void* r = (void*)p;
        p += (bytes + 255) & ~(size_t)255;
        return r;
    };
    __bf16*   Sx     = (__bf16*)  alloc((size_t)N * KTOT * sizeof(__bf16));
    __bf16*   xb     = (__bf16*)  alloc((size_t)N * DIM * sizeof(__bf16));
    unsigned* packed = (unsigned*)alloc((size_t)E * sizeof(unsigned));
    int*      degi   = (int*)     alloc((size_t)N * sizeof(int));
    int*      offs   = (int*)     alloc((size_t)N * sizeof(int));
    int*      cursor = (int*)     alloc((size_t)N * sizeof(int));
    float*    invdeg = (float*)   alloc((size_t)N * sizeof(float));
    int*      bsum   = (int*)     alloc(1024 * sizeof(int));

    int nb = (N + 255) / 256;

    hipMemsetAsync(degi,   0, (size_t)N * sizeof(int), stream);
    hipMemsetAsync(cursor, 0, (size_t)N * sizeof(int), stream);

    deg_kernel<<<(E + 255) / 256, 256, 0, stream>>>(dst, degi, E);
    invdeg_kernel<<<nb, 256, 0, stream>>>(degi, invdeg, N);
    scan1_kernel<<<nb, 256, 0, stream>>>(degi, offs, bsum, N);
    scan2_kernel<<<1, 512, 0, stream>>>(bsum, nb);
    scan3_kernel<<<nb, 256, 0, stream>>>(offs, bsum, N);
    bucket_kernel<<<(E + 255) / 256, 256, 0, stream>>>(src, dst, etyp, offs, cursor, packed, E);

    gather_kernel<<<((size_t)N * DIM + 255) / 256, 256, 0, stream>>>(x_idx, emb, xb, N);

    for (int l = 0; l < L; ++l) {
        aggregate_kernel<<<(N + 3) / 4, 256, 0, stream>>>(xb, packed, offs, degi, invdeg, Sx, N);
        gemm_kernel<<<512, 256, 0, stream>>>(Sx,
                                             weight + (size_t)l * NREL * DIM * DIM,
                                             root + (size_t)l * DIM * DIM,
                                             bias + (size_t)l * DIM,
                                             xb, N);
    }

    score_kernel<<<(T + 3) / 4, 256, 0, stream>>>(xb, ts, tt, out, T);
}

// Round 3
// 522.748 us; speedup vs baseline: 3.5002x; 1.0485x over previous
//
#include <hip/hip_runtime.h>
#include <hip/hip_bf16.h>

#define DIM 64
#define NREL 8
#define KTOT 576            // 8*64 relation block + 64 root block
#define WT_STRIDE 584       // padded LDS row stride (bf16), 292 dwords -> 2-way max

typedef __bf16 bf16x8 __attribute__((ext_vector_type(8)));
typedef float  f32x4  __attribute__((ext_vector_type(4)));

// ---------------- histogram over (dst, rel) ----------------
__global__ __launch_bounds__(256) void hist_kernel(const int* __restrict__ dst,
                                                   const int* __restrict__ et,
                                                   int* __restrict__ deg8, int E) {
    int i = blockIdx.x * 256 + threadIdx.x;
    if (i < E) atomicAdd(&deg8[dst[i] * 8 + et[i]], 1);
}

// ---------------- per-dst totals + inv_deg ----------------
__global__ __launch_bounds__(256) void sum8_kernel(const int* __restrict__ deg8,
                                                   int* __restrict__ degi,
                                                   float* __restrict__ invdeg, int N) {
    int d = blockIdx.x * 256 + threadIdx.x;
    if (d >= N) return;
    int s = 0;
#pragma unroll
    for (int r = 0; r < NREL; ++r) s += deg8[d * 8 + r];
    degi[d] = s;
    invdeg[d] = 1.0f / fmaxf((float)s, 1.0f);
}

// ---------------- 3-kernel exclusive scan over degi ----------------
__global__ __launch_bounds__(256) void scan1_kernel(const int* __restrict__ degi,
                                                    int* __restrict__ offs,
                                                    int* __restrict__ bsum, int N) {
    __shared__ int sd[256];
    int tid = threadIdx.x;
    int i = blockIdx.x * 256 + tid;
    int v = (i < N) ? degi[i] : 0;
    sd[tid] = v;
    __syncthreads();
#pragma unroll
    for (int off = 1; off < 256; off <<= 1) {
        int t = (tid >= off) ? sd[tid - off] : 0;
        __syncthreads();
        sd[tid] += t;
        __syncthreads();
    }
    if (i < N) offs[i] = sd[tid] - v;
    if (tid == 255) bsum[blockIdx.x] = sd[255];
}

__global__ __launch_bounds__(512) void scan2_kernel(int* __restrict__ bsum, int nb) {
    __shared__ int sd[512];
    int tid = threadIdx.x;
    int v = (tid < nb) ? bsum[tid] : 0;
    sd[tid] = v;
    __syncthreads();
#pragma unroll
    for (int off = 1; off < 512; off <<= 1) {
        int t = (tid >= off) ? sd[tid - off] : 0;
        __syncthreads();
        sd[tid] += t;
        __syncthreads();
    }
    if (tid < nb) bsum[tid] = sd[tid] - v;
}

__global__ __launch_bounds__(256) void scan3_kernel(int* __restrict__ offs,
                                                    const int* __restrict__ bsum, int N) {
    int i = blockIdx.x * 256 + threadIdx.x;
    if (i < N) offs[i] += bsum[blockIdx.x];
}

// ---------------- rp[d*8+r] = offs[d] + prefix(deg8[d][0..r]) ----------------
__global__ __launch_bounds__(256) void rpbuild_kernel(const int* __restrict__ deg8,
                                                      const int* __restrict__ offs,
                                                      int* __restrict__ rp, int N, int E) {
    int d = blockIdx.x * 256 + threadIdx.x;
    if (d >= N) return;
    int base = offs[d];
    int run = 0;
#pragma unroll
    for (int r = 0; r < NREL; ++r) {
        rp[d * 8 + r] = base + run;
        run += deg8[d * 8 + r];
    }
    if (d == 0) rp[(size_t)N * 8] = E;
}

// ---------------- bucket: srcs sorted by (dst, rel) ----------------
__global__ __launch_bounds__(256) void bucket_kernel(const int* __restrict__ src,
                                                     const int* __restrict__ dst,
                                                     const int* __restrict__ et,
                                                     const int* __restrict__ rp,
                                                     int* __restrict__ cursor8,
                                                     int* __restrict__ srcs, int E) {
    int i = blockIdx.x * 256 + threadIdx.x;
    if (i >= E) return;
    int cell = dst[i] * 8 + et[i];
    int p = rp[cell] + atomicAdd(&cursor8[cell], 1);
    srcs[p] = src[i];
}

// ---------------- initial gather: xb = bf16(node_emb[x_idx]) ----------------
__global__ __launch_bounds__(256) void gather_kernel(const int* __restrict__ x_idx,
                                                     const float* __restrict__ emb,
                                                     __bf16* __restrict__ xb, int N) {
    int i = blockIdx.x * 256 + threadIdx.x;
    if (i >= N * DIM) return;
    int n = i >> 6;
    int c = i & 63;
    xb[i] = (__bf16)emb[(size_t)x_idx[n] * DIM + c];
}

// ---------------- aggregate: one wave per dst, rel-sorted CSR, single accumulator
__global__ __launch_bounds__(256) void aggregate_kernel(const __bf16* __restrict__ xb,
                                                        const int* __restrict__ srcs,
                                                        const int* __restrict__ rp,
                                                        const float* __restrict__ invdeg,
                                                        __bf16* __restrict__ Sx, int N) {
    int d0 = blockIdx.x * 4 + (threadIdx.x >> 6);
    int d = __builtin_amdgcn_readfirstlane(d0);   // wave-uniform -> scalar loads below
    if (d >= N) return;
    int lane = threadIdx.x & 63;
    float inv = invdeg[d];
    __bf16* row = Sx + (size_t)d * KTOT;
    int b_next = rp[d * 8];
#pragma unroll
    for (int r = 0; r < NREL; ++r) {
        int b0 = b_next;
        b_next = rp[d * 8 + r + 1];
        float acc = 0.f;
        for (int j = b0; j < b_next; ++j) {
            int s = srcs[j];                       // scalar load (uniform addr)
            acc += (float)xb[(size_t)s * DIM + lane];
        }
        row[r * 64 + lane] = (__bf16)(acc * inv);
    }
    row[512 + lane] = xb[(size_t)d * DIM + lane];
}

// ---------------- GEMM: xout = relu(Sx[N,576] @ Wcat[576,64] + bias), bf16 MFMA
__global__ __launch_bounds__(256) void gemm_kernel(const __bf16* __restrict__ Sx,
                                                   const float* __restrict__ weight_l, // [8,64,64]
                                                   const float* __restrict__ root_l,   // [64,64]
                                                   const float* __restrict__ bias_l,   // [64]
                                                   __bf16* __restrict__ xout, int N) {
    __shared__ __bf16 Wt[64 * WT_STRIDE];

    for (int idx = threadIdx.x; idx < KTOT * 64; idx += 256) {
        int k = idx >> 6;
        int c = idx & 63;
        float w = (k < 512) ? weight_l[((k >> 6) << 12) + ((k & 63) << 6) + c]
                            : root_l[((k - 512) << 6) + c];
        Wt[c * WT_STRIDE + k] = (__bf16)w;
    }
    __syncthreads();

    int wave = threadIdx.x >> 6;
    int lane = threadIdx.x & 63;
    int l15 = lane & 15;
    int lg  = lane >> 4;
    int ntiles = (N + 63) >> 6;

    for (int tile = blockIdx.x; tile < ntiles; tile += gridDim.x) {
        int n0 = tile * 64;
        int row_a = n0 + 16 * wave + l15;
        if (row_a >= N) row_a = N - 1;
        const __bf16* arow = Sx + (size_t)row_a * KTOT + lg * 8;

        f32x4 acc[4];
#pragma unroll
        for (int t = 0; t < 4; ++t) acc[t] = (f32x4){0.f, 0.f, 0.f, 0.f};

#pragma unroll
        for (int k0 = 0; k0 < KTOT; k0 += 32) {
            bf16x8 av = *reinterpret_cast<const bf16x8*>(arow + k0);
#pragma unroll
            for (int t = 0; t < 4; ++t) {
                bf16x8 bv = *reinterpret_cast<const bf16x8*>(
                    &Wt[(16 * t + l15) * WT_STRIDE + k0 + lg * 8]);
                acc[t] = __builtin_amdgcn_mfma_f32_16x16x32_bf16(av, bv, acc[t], 0, 0, 0);
            }
        }

#pragma unroll
        for (int t = 0; t < 4; ++t) {
            int c = 16 * t + l15;
            float b = bias_l[c];
#pragma unroll
            for (int i = 0; i < 4; ++i) {
                int n = n0 + 16 * wave + 4 * lg + i;
                if (n < N) {
                    float v = acc[t][i] + b;
                    xout[(size_t)n * DIM + c] = (__bf16)fmaxf(v, 0.f);
                }
            }
        }
    }
}

// ---------------- score ----------------
__global__ __launch_bounds__(256) void score_kernel(const __bf16* __restrict__ xb,
                                                    const int* __restrict__ s,
                                                    const int* __restrict__ t,
                                                    float* __restrict__ out, int T) {
    int i = blockIdx.x * 4 + (threadIdx.x >> 6);
    if (i >= T) return;
    int lane = threadIdx.x & 63;
    float p = (float)xb[(size_t)s[i] * DIM + lane] * (float)xb[(size_t)t[i] * DIM + lane];
#pragma unroll
    for (int off = 32; off > 0; off >>= 1) p += __shfl_down(p, off, 64);
    if (lane == 0) out[i] = p;
}

extern "C" void kernel_launch(void* const* d_in, const int* in_sizes, int n_in,
                              void* d_out, int out_size, void* d_ws, size_t ws_size,
                              hipStream_t stream) {
    const int*   x_idx  = (const int*)d_in[0];
    const int*   eidx   = (const int*)d_in[1];   // [2,E]
    const int*   etyp   = (const int*)d_in[2];   // [E]
    const int*   tidx   = (const int*)d_in[3];   // [2,T]
    const float* emb    = (const float*)d_in[4]; // [N,64]
    const float* weight = (const float*)d_in[5]; // [L,8,64,64]
    const float* root   = (const float*)d_in[6]; // [L,64,64]
    const float* bias   = (const float*)d_in[7]; // [L,64]

    int N = in_sizes[0];
    int E = in_sizes[2];
    int T = in_sizes[3] / 2;
    int L = in_sizes[5] / (NREL * DIM * DIM);

    const int* src = eidx;
    const int* dst = eidx + E;
    const int* ts  = tidx;
    const int* tt  = tidx + T;
    float* out = (float*)d_out;

    // ---- workspace carve-up ----
    char* p = (char*)d_ws;
    auto alloc = [&](size_t bytes) -> void* {
        void* r = (void*)p;
        p += (bytes + 255) & ~(size_t)255;
        return r;
    };
    __bf16* Sx     = (__bf16*)alloc((size_t)N * KTOT * sizeof(__bf16));
    __bf16* xb     = (__bf16*)alloc((size_t)N * DIM * sizeof(__bf16));
    int*    srcs   = (int*)   alloc((size_t)E * sizeof(int));
    int*    deg8   = (int*)   alloc((size_t)N * 8 * sizeof(int));   // reused as cursor8
    int*    rp     = (int*)   alloc(((size_t)N * 8 + 1) * sizeof(int));
    int*    degi   = (int*)   alloc((size_t)N * sizeof(int));
    int*    offs   = (int*)   alloc((size_t)N * sizeof(int));
    float*  invdeg = (float*) alloc((size_t)N * sizeof(float));
    int*    bsum   = (int*)   alloc(1024 * sizeof(int));

    int nb = (N + 255) / 256;

    hipMemsetAsync(deg8, 0, (size_t)N * 8 * sizeof(int), stream);
    hist_kernel<<<(E + 255) / 256, 256, 0, stream>>>(dst, etyp, deg8, E);
    sum8_kernel<<<nb, 256, 0, stream>>>(deg8, degi, invdeg, N);
    scan1_kernel<<<nb, 256, 0, stream>>>(degi, offs, bsum, N);
    scan2_kernel<<<1, 512, 0, stream>>>(bsum, nb);
    scan3_kernel<<<nb, 256, 0, stream>>>(offs, bsum, N);
    rpbuild_kernel<<<nb, 256, 0, stream>>>(deg8, offs, rp, N, E);
    // deg8 no longer needed -> reuse as cursor8
    hipMemsetAsync(deg8, 0, (size_t)N * 8 * sizeof(int), stream);
    bucket_kernel<<<(E + 255) / 256, 256, 0, stream>>>(src, dst, etyp, rp, deg8, srcs, E);

    gather_kernel<<<((size_t)N * DIM + 255) / 256, 256, 0, stream>>>(x_idx, emb, xb, N);

    for (int l = 0; l < L; ++l) {
        aggregate_kernel<<<(N + 3) / 4, 256, 0, stream>>>(xb, srcs, rp, invdeg, Sx, N);
        gemm_kernel<<<512, 256, 0, stream>>>(Sx,
                                             weight + (size_t)l * NREL * DIM * DIM,
                                             root + (size_t)l * DIM * DIM,
                                             bias + (size_t)l * DIM,
                                             xb, N);
    }

    score_kernel<<<(T + 3) / 4, 256, 0, stream>>>(xb, ts, tt, out, T);
}